// Round 5
// baseline (210.004 us; speedup 1.0000x reference)
//
#include <hip/hip_runtime.h>

#define NT 32768
#define DI 36
#define HH 64
#define G3 192
#define LH 20

typedef __attribute__((ext_vector_type(8))) short bf16x8;
typedef __attribute__((ext_vector_type(4))) float f32x4;
typedef __attribute__((ext_vector_type(4))) int int4v;
union frag_cast { int4v i4; bf16x8 h8; };

__device__ __forceinline__ unsigned f2u(float f) { union { float f; unsigned u; } x; x.f = f; return x.u; }
__device__ __forceinline__ float u2f(unsigned u) { union { float f; unsigned u; } x; x.u = u; return x.f; }
__device__ __forceinline__ float fast_sigmoid(float x) {
    return __builtin_amdgcn_rcpf(1.f + __builtin_amdgcn_exp2f(-1.44269504089f * x));
}
__device__ __forceinline__ float fast_tanh(float x) {
    return 1.f - 2.f * __builtin_amdgcn_rcpf(1.f + __builtin_amdgcn_exp2f(2.88539008178f * x));
}

// Kernel 1: gi2[t][j] = emb[t,:].W_ih[j,:] + b_ih[j] + (j<128 ? b_hh[j] : 0)
// (t-major, j contiguous: gru's MFMA acc-init is then one b128 per tile).
// Blocks 0..47 also emit one W_hh fragment each (parallel — R3/R4's serial
// block-0 wfrag tail was ~20us of hidden runtime).
// Fragment convention (verified R3): A[m=16mt+(l&15)][k=32kt+8(l>>4)+jj];
// fb = mt*2+kt for hi, 48.. for lo (hi=trunc16, lo=v-hi, lo compensates).
__global__ __launch_bounds__(192, 2) void prep_kernel(
    const float* __restrict__ emb, const float* __restrict__ W_ih,
    const float* __restrict__ b_ih, const float* __restrict__ b_hh,
    const float* __restrict__ W_hh,
    float* __restrict__ gi2, int4v* __restrict__ wfrag)
{
    __shared__ float L[DI * 193 + DI * 36];
    float* const Wt = L;              // [k][j]  stride 193
    float* const Et = L + DI * 193;   // [k][ti] stride 36
    const int tid = threadIdx.x;
    const int t0 = blockIdx.x * 32;

    for (int i = tid; i < G3 * DI; i += 192)
        Wt[(i % DI) * 193 + i / DI] = W_ih[i];
    for (int i = tid; i < 32 * DI; i += 192)
        Et[(i % DI) * 36 + i / DI] = emb[(size_t)t0 * DI + i];
    __syncthreads();

    float acc[32];
#pragma unroll
    for (int i = 0; i < 32; ++i) acc[i] = 0.f;
    for (int k = 0; k < DI; ++k) {
        const float w = Wt[k * 193 + tid];
#pragma unroll
        for (int i4 = 0; i4 < 8; ++i4) {
            const float4 e = *(const float4*)&Et[k * 36 + i4 * 4];  // broadcast
            acc[i4 * 4 + 0] = fmaf(e.x, w, acc[i4 * 4 + 0]);
            acc[i4 * 4 + 1] = fmaf(e.y, w, acc[i4 * 4 + 1]);
            acc[i4 * 4 + 2] = fmaf(e.z, w, acc[i4 * 4 + 2]);
            acc[i4 * 4 + 3] = fmaf(e.w, w, acc[i4 * 4 + 3]);
        }
    }
    const float bias = b_ih[tid] + (tid < 128 ? b_hh[tid] : 0.f);
#pragma unroll
    for (int i = 0; i < 32; ++i)
        gi2[(size_t)(t0 + i) * G3 + tid] = acc[i] + bias;   // 768B/row coalesced

    // parallel W_hh fragment emit: one fragment per block, 64 lanes
    if (blockIdx.x < 48 && tid < 64) {
        const int fb = blockIdx.x;
        const bool is_lo = fb >= 24;
        const int mtkt = is_lo ? fb - 24 : fb;
        const int mt = mtkt >> 1, kt = mtkt & 1;
        const int m = mt * 16 + (tid & 15);
        const int k0 = kt * 32 + (tid >> 4) * 8;
        unsigned short e[8];
#pragma unroll
        for (int jj = 0; jj < 8; ++jj) {
            const float v = W_hh[m * HH + k0 + jj];
            const unsigned hv = f2u(v);
            if (!is_lo) e[jj] = (unsigned short)(hv >> 16);              // trunc hi
            else        e[jj] = (unsigned short)(f2u(v - u2f(hv & 0xFFFF0000u)) >> 16);
        }
        int4v p;
        p.x = e[0] | ((unsigned)e[1] << 16); p.y = e[2] | ((unsigned)e[3] << 16);
        p.z = e[4] | ((unsigned)e[5] << 16); p.w = e[6] | ((unsigned)e[7] << 16);
        wfrag[fb * 64 + tid] = p;
    }
}

// Main kernel: 512 blocks x 256 thr; each WAVE independently owns 16 timesteps
// (t = 64*blk + 16*w + li). NO barriers in the 20-step loop: the h -> B-frag
// transform round-trips a wave-PRIVATE LDS buffer (same-wave DS ops are FIFO).
// Per step per wave: 12 b128 gi loads (acc-init!), 4 b128 h reads, 24 b128
// Wlo reads (LDS, block-shared), 72 MFMA, 16-h elementwise, 8 b64 h writes.
__global__ __launch_bounds__(256, 2) void gru_kernel(
    const float* __restrict__ gi2, const int4v* __restrict__ wfrag,
    const float* __restrict__ b_hh, const float* __restrict__ W1,
    const float* __restrict__ b1, const float* __restrict__ W2,
    const float* __restrict__ b2, const int* __restrict__ dones,
    float* __restrict__ out)
{
    __shared__ __align__(16) int4v WloS[24 * 64];               // 24.6 KB shared
    __shared__ __align__(16) unsigned short Hb[4][2][16 * 72];  // 4.6 KB/wave

    const int tid = threadIdx.x;
    const int lane = tid & 63;
    const int w = tid >> 6;
    const int li = lane & 15;
    const int q = lane >> 4;
    const int t = blockIdx.x * 64 + w * 16 + li;   // this thread's timestep

    for (int i = tid; i < 24 * 64; i += 256)       // stage Wlo frags
        WloS[i] = wfrag[24 * 64 + i];

    bf16x8 whi[12][2];                             // Whi frags in registers
#pragma unroll
    for (int mt = 0; mt < 12; ++mt)
#pragma unroll
        for (int kt = 0; kt < 2; ++kt) {
            frag_cast c; c.i4 = wfrag[(mt * 2 + kt) * 64 + lane];
            whi[mt][kt] = c.h8;
        }

    // window start: only dones[t-19 .. t-1] matter
    int lo0 = t - (LH - 1); if (lo0 < 0) lo0 = 0;
    int wstart = lo0;
    for (int j = lo0; j < t; ++j)
        wstart = (dones[j] != 0) ? (j + 1) : wstart;
    const int sfr = wstart - (t - (LH - 1));       // first valid window step

    f32x4 bnv[4];                                  // n-gate acc init = b_hh_n
#pragma unroll
    for (int mq = 0; mq < 4; ++mq)
        bnv[mq] = *(const f32x4*)&b_hh[128 + 16 * mq + 4 * q];

    __syncthreads();                               // WloS staged (only barrier)

    unsigned short* const HbHi = &Hb[w][0][0];
    unsigned short* const HbLo = &Hb[w][1][0];

    float h[16];
#pragma unroll
    for (int i = 0; i < 16; ++i) h[i] = 0.f;

    for (int s = 0; s < LH; ++s) {
        int g = t - (LH - 1) + s; g = g < 0 ? 0 : g;   // clamped; masked by sfr
        const float* gp = gi2 + (size_t)g * G3;
        f32x4 accR[4], accZ[4], accN[4], ginv[4];
#pragma unroll
        for (int mq = 0; mq < 4; ++mq) {
            accR[mq] = *(const f32x4*)(gp + 16 * mq + 4 * q);        // gir+bias
            accZ[mq] = *(const f32x4*)(gp + 64 + 16 * mq + 4 * q);   // giz+bias
            ginv[mq] = *(const f32x4*)(gp + 128 + 16 * mq + 4 * q);  // gin+b_ih
            accN[mq] = bnv[mq];
        }
        if (s > 0) {
            const bf16x8 bh0 = *(const bf16x8*)&HbHi[li * 72 + 8 * q];
            const bf16x8 bh1 = *(const bf16x8*)&HbHi[li * 72 + 32 + 8 * q];
            const bf16x8 bl0 = *(const bf16x8*)&HbLo[li * 72 + 8 * q];
            const bf16x8 bl1 = *(const bf16x8*)&HbLo[li * 72 + 32 + 8 * q];
#pragma unroll
            for (int mt = 0; mt < 12; ++mt) {
                f32x4 a = (mt < 4) ? accR[mt] : (mt < 8) ? accZ[mt - 4] : accN[mt - 8];
                frag_cast w0, w1;
                w0.i4 = WloS[(mt * 2 + 0) * 64 + lane];
                w1.i4 = WloS[(mt * 2 + 1) * 64 + lane];
                a = __builtin_amdgcn_mfma_f32_16x16x32_bf16(whi[mt][0], bh0, a, 0, 0, 0);
                a = __builtin_amdgcn_mfma_f32_16x16x32_bf16(whi[mt][1], bh1, a, 0, 0, 0);
                a = __builtin_amdgcn_mfma_f32_16x16x32_bf16(whi[mt][0], bl0, a, 0, 0, 0);
                a = __builtin_amdgcn_mfma_f32_16x16x32_bf16(whi[mt][1], bl1, a, 0, 0, 0);
                a = __builtin_amdgcn_mfma_f32_16x16x32_bf16(w0.h8, bh0, a, 0, 0, 0);
                a = __builtin_amdgcn_mfma_f32_16x16x32_bf16(w1.h8, bh1, a, 0, 0, 0);
                if (mt < 4) accR[mt] = a; else if (mt < 8) accZ[mt - 4] = a; else accN[mt - 8] = a;
            }
        }
        const bool valid = (s >= sfr);
#pragma unroll
        for (int mq = 0; mq < 4; ++mq)
#pragma unroll
            for (int rr = 0; rr < 4; ++rr) {
                const float r  = fast_sigmoid(accR[mq][rr]);
                const float z  = fast_sigmoid(accZ[mq][rr]);
                const float nc = fast_tanh(ginv[mq][rr] + r * accN[mq][rr]);
                const float hn = fmaf(z, h[mq * 4 + rr] - nc, nc);
                h[mq * 4 + rr] = valid ? hn : h[mq * 4 + rr];
            }
        if (s < LH - 1) {
#pragma unroll
            for (int mq = 0; mq < 4; ++mq) {       // trunc-split pack via v_perm
                const unsigned u0 = f2u(h[mq * 4 + 0]), u1 = f2u(h[mq * 4 + 1]);
                const unsigned u2 = f2u(h[mq * 4 + 2]), u3 = f2u(h[mq * 4 + 3]);
                uint2 ph, pl;
                ph.x = __builtin_amdgcn_perm(u1, u0, 0x07060302u);
                ph.y = __builtin_amdgcn_perm(u3, u2, 0x07060302u);
                const unsigned l0 = f2u(h[mq * 4 + 0] - u2f(u0 & 0xFFFF0000u));
                const unsigned l1 = f2u(h[mq * 4 + 1] - u2f(u1 & 0xFFFF0000u));
                const unsigned l2 = f2u(h[mq * 4 + 2] - u2f(u2 & 0xFFFF0000u));
                const unsigned l3 = f2u(h[mq * 4 + 3] - u2f(u3 & 0xFFFF0000u));
                pl.x = __builtin_amdgcn_perm(l1, l0, 0x07060302u);
                pl.y = __builtin_amdgcn_perm(l3, l2, 0x07060302u);
                *(uint2*)&HbHi[li * 72 + 16 * mq + 4 * q] = ph;
                *(uint2*)&HbLo[li * 72 + 16 * mq + 4 * q] = pl;
            }
        }
    }

    // ---- MLP (wave-private, no barriers) ----
    float* const Hf = (float*)&Hb[w][0][0];        // [t][k] stride 68 (4352B)
#pragma unroll
    for (int mq = 0; mq < 4; ++mq) {
        float4 st;
        st.x = h[mq * 4 + 0]; st.y = h[mq * 4 + 1];
        st.z = h[mq * 4 + 2]; st.w = h[mq * 4 + 3];
        *(float4*)&Hf[li * 68 + 16 * mq + 4 * q] = st;
    }
    // MLP1: thread -> column m = lane, all 16 t (LDS reads are broadcasts)
    float hid[16];
#pragma unroll
    for (int i = 0; i < 16; ++i) hid[i] = 0.f;
    for (int k4 = 0; k4 < 16; ++k4) {
        const float4 wv = *(const float4*)&W1[lane * HH + 4 * k4];
#pragma unroll
        for (int tt = 0; tt < 16; ++tt) {
            const float4 hv = *(const float4*)&Hf[tt * 68 + 4 * k4];
            hid[tt] += hv.x * wv.x + hv.y * wv.y + hv.z * wv.z + hv.w * wv.w;
        }
    }
    const float bb = b1[lane];
#pragma unroll
    for (int tt = 0; tt < 16; ++tt)                // overwrite region: Hid[t][m]
        Hf[tt * 68 + lane] = fmaxf(hid[tt] + bb, 0.f);
    // MLP2: thread (li,q) -> out[t][c=q]
    float o2 = b2[q];
    for (int m4 = 0; m4 < 16; ++m4) {
        const float4 hv = *(const float4*)&Hf[li * 68 + 4 * m4];
        const float4 wv = *(const float4*)&W2[q * HH + 4 * m4];
        o2 += hv.x * wv.x + hv.y * wv.y + hv.z * wv.z + hv.w * wv.w;
    }
    out[(size_t)t * 4 + q] = o2;                   // 256B/wave contiguous
}

extern "C" void kernel_launch(void* const* d_in, const int* in_sizes, int n_in,
                              void* d_out, int out_size, void* d_ws, size_t ws_size,
                              hipStream_t stream) {
    const float* emb  = (const float*)d_in[0];
    const float* W_ih = (const float*)d_in[1];
    const float* W_hh = (const float*)d_in[2];
    const float* b_ih = (const float*)d_in[3];
    const float* b_hh = (const float*)d_in[4];
    const float* W1   = (const float*)d_in[5];
    const float* b1   = (const float*)d_in[6];
    const float* W2   = (const float*)d_in[7];
    const float* b2   = (const float*)d_in[8];
    const int*   dn   = (const int*)d_in[9];

    float* gi2   = (float*)d_ws;                                 // 25.2 MB
    int4v* wfrag = (int4v*)((char*)d_ws + (size_t)NT * G3 * 4);  // +48 KB
    float* o     = (float*)d_out;

    prep_kernel<<<NT / 32, 192, 0, stream>>>(emb, W_ih, b_ih, b_hh, W_hh, gi2, wfrag);
    gru_kernel<<<NT / 64, 256, 0, stream>>>(gi2, wfrag, b_hh, W1, b1, W2, b2, dn, o);
}

// Round 6
// 171.369 us; speedup vs baseline: 1.2254x; 1.2254x over previous
//
#include <hip/hip_runtime.h>

#define NT 32768
#define DI 36
#define HH 64
#define G3 192
#define LH 20

typedef __attribute__((ext_vector_type(8))) short bf16x8;
typedef __attribute__((ext_vector_type(4))) float f32x4;
typedef __attribute__((ext_vector_type(4))) int int4v;
union frag_cast { int4v i4; bf16x8 h8; };

__device__ __forceinline__ unsigned f2u(float f) { union { float f; unsigned u; } x; x.f = f; return x.u; }
__device__ __forceinline__ float u2f(unsigned u) { union { float f; unsigned u; } x; x.u = u; return x.f; }
__device__ __forceinline__ unsigned short f2bf_rne(float f) {   // round-nearest-even
    union { float f; unsigned u; } x; x.f = f;
    unsigned r = x.u + 0x7FFFu + ((x.u >> 16) & 1u);
    return (unsigned short)(r >> 16);
}
__device__ __forceinline__ float fast_sigmoid(float x) {
    return __builtin_amdgcn_rcpf(1.f + __builtin_amdgcn_exp2f(-1.44269504089f * x));
}
__device__ __forceinline__ float fast_tanh(float x) {
    return 1.f - 2.f * __builtin_amdgcn_rcpf(1.f + __builtin_amdgcn_exp2f(2.88539008178f * x));
}

// Kernel 1: gi2[t][j] = emb[t,:].W_ih[j,:] + b_ih[j] + (j<128 ? b_hh[j] : 0)
// t-major so gru's acc-init is b128 loads. Blocks 0..23 emit W_hh hi-fragments
// (RNE bf16; no lo fragments this round — h stays split, W does not).
// Fragment convention (verified R3): A[m=16mt+(l&15)][k=32kt+8(l>>4)+jj].
__global__ __launch_bounds__(192, 2) void prep_kernel(
    const float* __restrict__ emb, const float* __restrict__ W_ih,
    const float* __restrict__ b_ih, const float* __restrict__ b_hh,
    const float* __restrict__ W_hh,
    float* __restrict__ gi2, int4v* __restrict__ wfrag)
{
    __shared__ float L[DI * 193 + DI * 36];
    float* const Wt = L;              // [k][j]  stride 193
    float* const Et = L + DI * 193;   // [k][ti] stride 36
    const int tid = threadIdx.x;
    const int t0 = blockIdx.x * 32;

    for (int i = tid; i < G3 * DI; i += 192)
        Wt[(i % DI) * 193 + i / DI] = W_ih[i];
    for (int i = tid; i < 32 * DI; i += 192)
        Et[(i % DI) * 36 + i / DI] = emb[(size_t)t0 * DI + i];
    __syncthreads();

    float acc[32];
#pragma unroll
    for (int i = 0; i < 32; ++i) acc[i] = 0.f;
    for (int k = 0; k < DI; ++k) {
        const float w = Wt[k * 193 + tid];
#pragma unroll
        for (int i4 = 0; i4 < 8; ++i4) {
            const float4 e = *(const float4*)&Et[k * 36 + i4 * 4];  // broadcast
            acc[i4 * 4 + 0] = fmaf(e.x, w, acc[i4 * 4 + 0]);
            acc[i4 * 4 + 1] = fmaf(e.y, w, acc[i4 * 4 + 1]);
            acc[i4 * 4 + 2] = fmaf(e.z, w, acc[i4 * 4 + 2]);
            acc[i4 * 4 + 3] = fmaf(e.w, w, acc[i4 * 4 + 3]);
        }
    }
    const float bias = b_ih[tid] + (tid < 128 ? b_hh[tid] : 0.f);
#pragma unroll
    for (int i = 0; i < 32; ++i)
        gi2[(size_t)(t0 + i) * G3 + tid] = acc[i] + bias;   // 768B/row coalesced

    // W_hh hi-fragments (RNE), one fragment per block, 64 lanes
    if (blockIdx.x < 24 && tid < 64) {
        const int mt = (int)blockIdx.x >> 1, kt = (int)blockIdx.x & 1;
        const int m = mt * 16 + (tid & 15);
        const int k0 = kt * 32 + (tid >> 4) * 8;
        unsigned short e[8];
#pragma unroll
        for (int jj = 0; jj < 8; ++jj)
            e[jj] = f2bf_rne(W_hh[m * HH + k0 + jj]);
        int4v p;
        p.x = e[0] | ((unsigned)e[1] << 16); p.y = e[2] | ((unsigned)e[3] << 16);
        p.z = e[4] | ((unsigned)e[5] << 16); p.w = e[6] | ((unsigned)e[7] << 16);
        wfrag[(int)blockIdx.x * 64 + tid] = p;
    }
}

// Main kernel: 512 blocks x 256 thr; each WAVE independently owns 16 timesteps.
// ZERO barriers: h round-trips a wave-private LDS buffer (same-wave DS = FIFO).
// blockIdx swizzled so consecutive-t blocks share an XCD: per-XCD gi slice
// = 3MB < 4MB L2 (R5's round-robin thrashed L2 -> 360MB FETCH).
// Per step/wave: 12 b128 gi loads (prefetched 1 step ahead), 4 b128 h reads,
// 48 MFMA (W hi x h hi/lo), 16-wide elementwise, 8 b64 h writes.
__global__ __launch_bounds__(256, 2) void gru_kernel(
    const float* __restrict__ gi2, const int4v* __restrict__ wfrag,
    const float* __restrict__ b_hh, const float* __restrict__ W1,
    const float* __restrict__ b1, const float* __restrict__ W2,
    const float* __restrict__ b2, const int* __restrict__ dones,
    float* __restrict__ out)
{
    __shared__ __align__(16) unsigned short Hb[4][2][16 * 72];  // 18.4 KB total

    const int tid = threadIdx.x;
    const int lane = tid & 63;
    const int w = tid >> 6;
    const int li = lane & 15;
    const int q = lane >> 4;
    const int blk = ((int)blockIdx.x & 7) * 64 + ((int)blockIdx.x >> 3);
    const int t = blk * 64 + w * 16 + li;

    bf16x8 whi[12][2];
#pragma unroll
    for (int mt = 0; mt < 12; ++mt)
#pragma unroll
        for (int kt = 0; kt < 2; ++kt) {
            frag_cast c; c.i4 = wfrag[(mt * 2 + kt) * 64 + lane];
            whi[mt][kt] = c.h8;
        }

    // window start: only dones[t-19 .. t-1] matter
    int lo0 = t - (LH - 1); if (lo0 < 0) lo0 = 0;
    int wstart = lo0;
    for (int j = lo0; j < t; ++j)
        wstart = (dones[j] != 0) ? (j + 1) : wstart;
    const int sfr = wstart - (t - (LH - 1));       // first valid window step

    f32x4 bnv[4];                                  // n-gate acc init = b_hh_n
#pragma unroll
    for (int mq = 0; mq < 4; ++mq)
        bnv[mq] = *(const f32x4*)&b_hh[128 + 16 * mq + 4 * q];

    unsigned short* const HbHi = &Hb[w][0][0];
    unsigned short* const HbLo = &Hb[w][1][0];

    float h[16];
#pragma unroll
    for (int i = 0; i < 16; ++i) h[i] = 0.f;

    f32x4 accR[4], accZ[4], accN[4], ginv[4];
    f32x4 gvR[4], gvZ[4], gvN[4];                  // prefetch buffer (s+1)

    // ---- s = 0 (h=0: no MFMA) ----
    {
        int g = t - (LH - 1); g = g < 0 ? 0 : g;
        const float* gp = gi2 + (size_t)g * G3;
#pragma unroll
        for (int mq = 0; mq < 4; ++mq) {
            accR[mq] = *(const f32x4*)(gp + 16 * mq + 4 * q);
            accZ[mq] = *(const f32x4*)(gp + 64 + 16 * mq + 4 * q);
            ginv[mq] = *(const f32x4*)(gp + 128 + 16 * mq + 4 * q);
            accN[mq] = bnv[mq];
        }
        const bool valid = (0 >= sfr);
#pragma unroll
        for (int mq = 0; mq < 4; ++mq)
#pragma unroll
            for (int rr = 0; rr < 4; ++rr) {
                const float r  = fast_sigmoid(accR[mq][rr]);
                const float z  = fast_sigmoid(accZ[mq][rr]);
                const float nc = fast_tanh(ginv[mq][rr] + r * accN[mq][rr]);
                h[mq * 4 + rr] = valid ? fmaf(z, 0.f - nc, nc) : 0.f;
            }
#pragma unroll
        for (int mq = 0; mq < 4; ++mq) {           // trunc-split pack via v_perm
            const unsigned u0 = f2u(h[mq * 4 + 0]), u1 = f2u(h[mq * 4 + 1]);
            const unsigned u2 = f2u(h[mq * 4 + 2]), u3 = f2u(h[mq * 4 + 3]);
            uint2 ph, pl;
            ph.x = __builtin_amdgcn_perm(u1, u0, 0x07060302u);
            ph.y = __builtin_amdgcn_perm(u3, u2, 0x07060302u);
            const unsigned l0 = f2u(h[mq * 4 + 0] - u2f(u0 & 0xFFFF0000u));
            const unsigned l1 = f2u(h[mq * 4 + 1] - u2f(u1 & 0xFFFF0000u));
            const unsigned l2 = f2u(h[mq * 4 + 2] - u2f(u2 & 0xFFFF0000u));
            const unsigned l3 = f2u(h[mq * 4 + 3] - u2f(u3 & 0xFFFF0000u));
            pl.x = __builtin_amdgcn_perm(l1, l0, 0x07060302u);
            pl.y = __builtin_amdgcn_perm(l3, l2, 0x07060302u);
            *(uint2*)&HbHi[li * 72 + 16 * mq + 4 * q] = ph;
            *(uint2*)&HbLo[li * 72 + 16 * mq + 4 * q] = pl;
        }
    }
    // prefetch gv for s = 1
    {
        int g = t - (LH - 1) + 1; g = g < 0 ? 0 : g;
        const float* gp = gi2 + (size_t)g * G3;
#pragma unroll
        for (int mq = 0; mq < 4; ++mq) {
            gvR[mq] = *(const f32x4*)(gp + 16 * mq + 4 * q);
            gvZ[mq] = *(const f32x4*)(gp + 64 + 16 * mq + 4 * q);
            gvN[mq] = *(const f32x4*)(gp + 128 + 16 * mq + 4 * q);
        }
    }

#pragma unroll 2
    for (int s = 1; s < LH; ++s) {
        // h fragments from previous step (wave-private LDS, FIFO-ordered)
        const bf16x8 bh0 = *(const bf16x8*)&HbHi[li * 72 + 8 * q];
        const bf16x8 bh1 = *(const bf16x8*)&HbHi[li * 72 + 32 + 8 * q];
        const bf16x8 bl0 = *(const bf16x8*)&HbLo[li * 72 + 8 * q];
        const bf16x8 bl1 = *(const bf16x8*)&HbLo[li * 72 + 32 + 8 * q];

        // consume prefetch into accumulators
#pragma unroll
        for (int mq = 0; mq < 4; ++mq) {
            accR[mq] = gvR[mq]; accZ[mq] = gvZ[mq];
            ginv[mq] = gvN[mq]; accN[mq] = bnv[mq];
        }
        // issue prefetch for s+1 (hidden under MFMA + elementwise)
        {
            int g = t - (LH - 1) + s + 1;
            g = g < 0 ? 0 : (g > NT - 1 ? NT - 1 : g);
            const float* gp = gi2 + (size_t)g * G3;
#pragma unroll
            for (int mq = 0; mq < 4; ++mq) {
                gvR[mq] = *(const f32x4*)(gp + 16 * mq + 4 * q);
                gvZ[mq] = *(const f32x4*)(gp + 64 + 16 * mq + 4 * q);
                gvN[mq] = *(const f32x4*)(gp + 128 + 16 * mq + 4 * q);
            }
        }
#pragma unroll
        for (int mt = 0; mt < 12; ++mt) {
            f32x4 a = (mt < 4) ? accR[mt] : (mt < 8) ? accZ[mt - 4] : accN[mt - 8];
            a = __builtin_amdgcn_mfma_f32_16x16x32_bf16(whi[mt][0], bh0, a, 0, 0, 0);
            a = __builtin_amdgcn_mfma_f32_16x16x32_bf16(whi[mt][1], bh1, a, 0, 0, 0);
            a = __builtin_amdgcn_mfma_f32_16x16x32_bf16(whi[mt][0], bl0, a, 0, 0, 0);
            a = __builtin_amdgcn_mfma_f32_16x16x32_bf16(whi[mt][1], bl1, a, 0, 0, 0);
            if (mt < 4) accR[mt] = a; else if (mt < 8) accZ[mt - 4] = a; else accN[mt - 8] = a;
        }
        const bool valid = (s >= sfr);
#pragma unroll
        for (int mq = 0; mq < 4; ++mq)
#pragma unroll
            for (int rr = 0; rr < 4; ++rr) {
                const float r  = fast_sigmoid(accR[mq][rr]);
                const float z  = fast_sigmoid(accZ[mq][rr]);
                const float nc = fast_tanh(ginv[mq][rr] + r * accN[mq][rr]);
                const float hn = fmaf(z, h[mq * 4 + rr] - nc, nc);
                h[mq * 4 + rr] = valid ? hn : h[mq * 4 + rr];
            }
        if (s < LH - 1) {
#pragma unroll
            for (int mq = 0; mq < 4; ++mq) {
                const unsigned u0 = f2u(h[mq * 4 + 0]), u1 = f2u(h[mq * 4 + 1]);
                const unsigned u2 = f2u(h[mq * 4 + 2]), u3 = f2u(h[mq * 4 + 3]);
                uint2 ph, pl;
                ph.x = __builtin_amdgcn_perm(u1, u0, 0x07060302u);
                ph.y = __builtin_amdgcn_perm(u3, u2, 0x07060302u);
                const unsigned l0 = f2u(h[mq * 4 + 0] - u2f(u0 & 0xFFFF0000u));
                const unsigned l1 = f2u(h[mq * 4 + 1] - u2f(u1 & 0xFFFF0000u));
                const unsigned l2 = f2u(h[mq * 4 + 2] - u2f(u2 & 0xFFFF0000u));
                const unsigned l3 = f2u(h[mq * 4 + 3] - u2f(u3 & 0xFFFF0000u));
                pl.x = __builtin_amdgcn_perm(l1, l0, 0x07060302u);
                pl.y = __builtin_amdgcn_perm(l3, l2, 0x07060302u);
                *(uint2*)&HbHi[li * 72 + 16 * mq + 4 * q] = ph;
                *(uint2*)&HbLo[li * 72 + 16 * mq + 4 * q] = pl;
            }
        }
    }

    // ---- MLP (wave-private, no barriers) ----
    float* const Hf = (float*)&Hb[w][0][0];        // [t][k] stride 68
#pragma unroll
    for (int mq = 0; mq < 4; ++mq) {
        float4 st;
        st.x = h[mq * 4 + 0]; st.y = h[mq * 4 + 1];
        st.z = h[mq * 4 + 2]; st.w = h[mq * 4 + 3];
        *(float4*)&Hf[li * 68 + 16 * mq + 4 * q] = st;
    }
    float hid[16];
#pragma unroll
    for (int i = 0; i < 16; ++i) hid[i] = 0.f;
    for (int k4 = 0; k4 < 16; ++k4) {
        const float4 wv = *(const float4*)&W1[lane * HH + 4 * k4];
#pragma unroll
        for (int tt = 0; tt < 16; ++tt) {
            const float4 hv = *(const float4*)&Hf[tt * 68 + 4 * k4];
            hid[tt] += hv.x * wv.x + hv.y * wv.y + hv.z * wv.z + hv.w * wv.w;
        }
    }
    const float bb = b1[lane];
#pragma unroll
    for (int tt = 0; tt < 16; ++tt)
        Hf[tt * 68 + lane] = fmaxf(hid[tt] + bb, 0.f);
    float o2 = b2[q];
    for (int m4 = 0; m4 < 16; ++m4) {
        const float4 hv = *(const float4*)&Hf[li * 68 + 4 * m4];
        const float4 wv = *(const float4*)&W2[q * HH + 4 * m4];
        o2 += hv.x * wv.x + hv.y * wv.y + hv.z * wv.z + hv.w * wv.w;
    }
    out[(size_t)t * 4 + q] = o2;

}

extern "C" void kernel_launch(void* const* d_in, const int* in_sizes, int n_in,
                              void* d_out, int out_size, void* d_ws, size_t ws_size,
                              hipStream_t stream) {
    const float* emb  = (const float*)d_in[0];
    const float* W_ih = (const float*)d_in[1];
    const float* W_hh = (const float*)d_in[2];
    const float* b_ih = (const float*)d_in[3];
    const float* b_hh = (const float*)d_in[4];
    const float* W1   = (const float*)d_in[5];
    const float* b1   = (const float*)d_in[6];
    const float* W2   = (const float*)d_in[7];
    const float* b2   = (const float*)d_in[8];
    const int*   dn   = (const int*)d_in[9];

    float* gi2   = (float*)d_ws;                                 // 25.2 MB
    int4v* wfrag = (int4v*)((char*)d_ws + (size_t)NT * G3 * 4);  // +24 KB
    float* o     = (float*)d_out;

    prep_kernel<<<NT / 32, 192, 0, stream>>>(emb, W_ih, b_ih, b_hh, W_hh, gi2, wfrag);
    gru_kernel<<<NT / 64, 256, 0, stream>>>(gi2, wfrag, b_hh, W1, b1, W2, b2, dn, o);
}